// Round 12
// baseline (295.723 us; speedup 1.0000x reference)
//
#include <hip/hip_runtime.h>
#include <math.h>

// Problem constants
#define Bq   256
#define Hd   2048
#define Ed   256
#define Ni   200000
#define Tt   4
#define NBITS 8
#define Kk   100
#define Mm   128            // rerank margin: top-128 by approx key superset of true top-100
#define CAPL 16384          // per-query compact candidate list capacity
#define CAPB 2048           // per-block LDS match buffer (slice expects ~194)
#define CAP2 4096           // select LDS collect capacity
#define NBINS 8192
#define NSLICE 16
#define ISLICE (Ni / NSLICE)   // 12500
#define IPB 64               // icode items per block (200000/64 = 3125 exact)
#define QPB 8                // qproj queries per block
#define QT  (Bq / QPB)       // 32 q-tiles
#define KC  16               // k-chunks
#define KCH (Hd / KC)        // 128

// ws layout (bytes) — total ~145.8 MB
#define OFF_QV64  0ull            // 256*256*8   = 524288
#define OFF_QC    524288ull       // 256*4       = 1024
#define OFF_IC    525312ull       // 200000*4    = 800000
#define OFF_CNT   1325312ull      // 256*4       = 1024
#define OFF_CAND  1326336ull      // 256*128*4   = 131072
#define OFF_LIST  103857408ull    // 256*16384*8  = 33554432
#define OFF_PART  137411840ull    // 16*256*256*8 = 8388608

__device__ __forceinline__ bool anybyte_eq(unsigned a, unsigned b) {
  unsigned x = a ^ b;
  return ((x - 0x01010101u) & ~x & 0x80808080u) != 0u;
}
__device__ __forceinline__ unsigned fkey(float s) {
  unsigned u = __float_as_uint(s);
  return (u & 0x80000000u) ? ~u : (u | 0x80000000u);
}

// histogram beta-find helper (shared across select/fallback)
__device__ __forceinline__ int find_beta(unsigned* hist, unsigned* partial_,
                                         int* sbeta, int tid, int target) {
  unsigned s = 0;
#pragma unroll 8
  for (int j = 0; j < 32; ++j) s += hist[tid * 32 + j];
  partial_[tid] = s;
  __syncthreads();
  if (tid == 0) {
    unsigned cum = 0;
    int c;
    for (c = 255; c > 0; --c) {
      if (cum + partial_[c] >= (unsigned)target) break;
      cum += partial_[c];
    }
    int b;
    for (b = c * 32 + 31; b > c * 32; --b) {
      if (cum + hist[b] >= (unsigned)target) break;
      cum += hist[b];
    }
    *sbeta = b;
  }
  __syncthreads();
  return *sbeta;
}

// ---------------------------------------------------------------------------
// Kernel A1: split-K f64 projection GEMM. grid (32 qtiles, 16 kchunks) x 256.
// ---------------------------------------------------------------------------
__global__ void __launch_bounds__(256) qproj_gemm(
    const float* __restrict__ hidden,
    const float* __restrict__ Wq,
    double* __restrict__ partial) {
  __shared__ float hs_t[KCH][QPB];   // [h][qq], 4 KB
  const int e = threadIdx.x;
  const int qbase = blockIdx.x * QPB;
  const int kc = blockIdx.y;

  for (int j = e; j < QPB * KCH; j += 256) {
    int qq = j >> 7, h = j & (KCH - 1);
    hs_t[h][qq] = hidden[(size_t)(qbase + qq) * Hd + kc * KCH + h];
  }
  __syncthreads();

  double acc[QPB];
#pragma unroll
  for (int qq = 0; qq < QPB; ++qq) acc[qq] = 0.0;

  for (int h = 0; h < KCH; ++h) {
    double w = (double)Wq[(size_t)(kc * KCH + h) * Ed + e];
    float4 ha = *reinterpret_cast<const float4*>(&hs_t[h][0]);
    float4 hb = *reinterpret_cast<const float4*>(&hs_t[h][4]);
    acc[0] = fma((double)ha.x, w, acc[0]);
    acc[1] = fma((double)ha.y, w, acc[1]);
    acc[2] = fma((double)ha.z, w, acc[2]);
    acc[3] = fma((double)ha.w, w, acc[3]);
    acc[4] = fma((double)hb.x, w, acc[4]);
    acc[5] = fma((double)hb.y, w, acc[5]);
    acc[6] = fma((double)hb.z, w, acc[6]);
    acc[7] = fma((double)hb.w, w, acc[7]);
  }

#pragma unroll
  for (int qq = 0; qq < QPB; ++qq)
    partial[((size_t)kc * Bq + qbase + qq) * Ed + e] = acc[qq];
}

// ---------------------------------------------------------------------------
// Kernel A2: finalize — sum 16 partials + LayerNorm + tanh + fused qcode.
// ---------------------------------------------------------------------------
__global__ void qproj_fin(const double* __restrict__ partial,
                          const float* __restrict__ bq,
                          const float* __restrict__ gamma,
                          const float* __restrict__ beta,
                          const float* __restrict__ proj,
                          float* __restrict__ out_qv,
                          double* __restrict__ qv64,
                          unsigned* __restrict__ qcp,
                          unsigned* __restrict__ cnt) {
  const int q = blockIdx.x, e = threadIdx.x;
  __shared__ double red[256];
  __shared__ double qd[256];
  __shared__ double s_mu, s_rs;

  if (e == 0) cnt[q] = 0u;

  double acc = 0.0;
#pragma unroll
  for (int kc = 0; kc < KC; ++kc)
    acc += partial[((size_t)kc * Bq + q) * Ed + e];
  acc += (double)bq[e];

  red[e] = acc;
  __syncthreads();
  for (int s = 128; s > 0; s >>= 1) {
    if (e < s) red[e] += red[e + s];
    __syncthreads();
  }
  if (e == 0) s_mu = red[0] / 256.0;
  __syncthreads();
  double d = acc - s_mu;
  red[e] = d * d;
  __syncthreads();
  for (int s = 128; s > 0; s >>= 1) {
    if (e < s) red[e] += red[e + s];
    __syncthreads();
  }
  if (e == 0) s_rs = 1.0 / sqrt(red[0] / 256.0 + 1e-5);
  __syncthreads();

  double y = (acc - s_mu) * s_rs * (double)gamma[e] + (double)beta[e];
  double t = tanh(y);
  out_qv[(size_t)q * Ed + e] = (float)t;
  qv64[(size_t)q * Ed + e] = t;
  qd[e] = t;
  __syncthreads();

  double dot = 0.0;
  if (e < 32) {
    const int tt = e >> 3, b = e & 7;
    const float* pp = proj + (size_t)tt * Ed * NBITS + b;
#pragma unroll 4
    for (int ee = 0; ee < Ed; ++ee)
      dot = fma(qd[ee], (double)pp[(size_t)ee * NBITS], dot);
  }
  unsigned long long mask = __ballot(e < 32 && dot > 0.0);
  if (e == 0) qcp[q] = (unsigned)mask;
}

// ---------------------------------------------------------------------------
// Kernel I (v9): f32 LDS tile, wave-uniform table -> proj in SGPRs.
// grid 3125 x 256. Tile [64][65] f32, 16.6 KB -> 8 blocks/CU.
// f32 accumulate, thr 2e-4, per-bit f64 recompute (R4-R6 proven exact).
// ---------------------------------------------------------------------------
__global__ void __launch_bounds__(256) icode_kernel(
    const float* __restrict__ item,
    const float* __restrict__ proj,
    unsigned* __restrict__ icodes) {
  __shared__ float ts[IPB * 65];       // 16640 B
  __shared__ unsigned icode_s[IPB];
  const int tid = threadIdx.x;
  const int base = blockIdx.x * IPB;
  const int il = tid & 63;
  const int t = __builtin_amdgcn_readfirstlane(tid >> 6);
  const float* pt = proj + (size_t)t * (Ed * NBITS);   // [e][8]

  if (tid < IPB) icode_s[tid] = 0u;

  float acc[8];
#pragma unroll
  for (int b = 0; b < 8; ++b) acc[b] = 0.0f;

  for (int c = 0; c < 4; ++c) {        // 4 chunks of 64 e
    __syncthreads();
#pragma unroll
    for (int rep = 0; rep < 16; ++rep) {
      const int fi = rep * 256 + tid;
      const int row = fi >> 6, e = fi & 63;
      ts[row * 65 + e] = item[(size_t)(base + row) * Ed + c * 64 + e];
    }
    __syncthreads();

#pragma unroll 8
    for (int e = 0; e < 64; ++e) {
      const float av = ts[il * 65 + e];
      const float4 pa = *reinterpret_cast<const float4*>(&pt[(size_t)(c * 64 + e) * 8]);
      const float4 pb = *reinterpret_cast<const float4*>(&pt[(size_t)(c * 64 + e) * 8 + 4]);
      acc[0] = fmaf(av, pa.x, acc[0]);
      acc[1] = fmaf(av, pa.y, acc[1]);
      acc[2] = fmaf(av, pa.z, acc[2]);
      acc[3] = fmaf(av, pa.w, acc[3]);
      acc[4] = fmaf(av, pb.x, acc[4]);
      acc[5] = fmaf(av, pb.y, acc[5]);
      acc[6] = fmaf(av, pb.z, acc[6]);
      acc[7] = fmaf(av, pb.w, acc[7]);
    }
  }

  unsigned byte = 0, bl = 0;
#pragma unroll
  for (int b = 0; b < 8; ++b) {
    byte |= (acc[b] > 0.0f ? 1u : 0u) << b;
    bl |= (fabsf(acc[b]) < 2e-4f ? 1u : 0u) << b;
  }

  if (bl) {   // rare exact f64 path (~0.016% of bits)
    const int gi = base + il;
    const float* er = item + (size_t)gi * Ed;
    while (bl) {
      const int b = __builtin_ctz(bl);
      bl &= bl - 1;
      const float* pp = pt + b;
      double a = 0.0;
      for (int e2 = 0; e2 < Ed; ++e2)
        a = fma((double)er[e2], (double)pp[(size_t)e2 * NBITS], a);
      if (a > 0.0) byte |= 1u << b; else byte &= ~(1u << b);
    }
  }

  atomicOr(&icode_s[il], byte << (8 * t));
  __syncthreads();
  if (tid < IPB) icodes[base + tid] = icode_s[tid];
}

// ---------------------------------------------------------------------------
// Kernel F (v3): scan/process-decoupled match + scoring, deep-pipelined.
// grid (256 q, 16 slices) x 256. Scan: ballot + mbcnt-ranked parallel append.
// Process: 32 x 8-lane groups, unroll-2 dual-dot (16 row-loads in flight),
// 3-step shfl reduce. Flush: ONE global atomic + coalesced.
// ---------------------------------------------------------------------------
__global__ void __launch_bounds__(256) score_kernel(
    const float* __restrict__ qvf,
    const float* __restrict__ item,
    const unsigned* __restrict__ icodes,
    const unsigned* __restrict__ qcp,
    unsigned* __restrict__ cnt,
    unsigned long long* __restrict__ list) {
  __shared__ unsigned long long buf[CAPB];   // 16 KB: ids, then (key|~id)
  __shared__ int lcnt;
  __shared__ unsigned sbase;

  const int tid = threadIdx.x;
  const int q = blockIdx.x, sl = blockIdx.y;
  const int l = tid & 63, wid = tid >> 6;
  const int k = tid & 7;             // lane within 8-group
  const int gg = tid >> 3;           // group id 0..31

  if (tid == 0) lcnt = 0;
  const unsigned qc = qcp[q];

  // per-thread qv fragment: elements (c*8+k)*4 .. +4, c = 0..7 (32 VGPR)
  float4 qv[8];
#pragma unroll
  for (int c = 0; c < 8; ++c)
    qv[c] = *reinterpret_cast<const float4*>(&qvf[(size_t)q * Ed + (c * 8 + k) * 4]);
  __syncthreads();

  // ---- scan phase: ballot + ranked parallel append ----
  const int i0 = sl * ISLICE, i1 = i0 + ISLICE;
  for (int bse = i0 + wid * 64; bse < i1; bse += 256) {
    const int i = bse + l;
    bool m = (i < i1) && anybyte_eq(qc, icodes[i]);
    unsigned long long mask = __ballot(m);
    if (mask) {
      int base_ = 0;
      if (l == 0) base_ = atomicAdd(&lcnt, __popcll(mask));
      base_ = __shfl(base_, 0);
      if (m) {
        int rank = __popcll(mask & ((1ull << l) - 1ull));
        int pos = base_ + rank;
        if (pos < CAPB) buf[pos] = (unsigned long long)(unsigned)i;
      }
    }
  }
  __syncthreads();

  if (lcnt > CAPB) {   // overflow: force brute-force fallback for q
    if (tid == 0) atomicAdd(&cnt[q], (unsigned)(CAPL + 1));
    return;
  }
  const int nl = lcnt;

  // ---- process phase: 32 groups x dual-dot pipeline ----
  for (int b = gg; b < nl; b += 64) {
    const int b1 = b + 32;
    const bool has1 = (b1 < nl);
    const int id0 = (int)(unsigned)buf[b];
    const int id1 = has1 ? (int)(unsigned)buf[b1] : id0;
    const float* r0 = item + (size_t)id0 * Ed;
    const float* r1 = item + (size_t)id1 * Ed;
    float p0 = 0.0f, p1 = 0.0f;
#pragma unroll
    for (int c = 0; c < 8; ++c) {
      const float4 e0 = *reinterpret_cast<const float4*>(&r0[(c * 8 + k) * 4]);
      const float4 e1 = *reinterpret_cast<const float4*>(&r1[(c * 8 + k) * 4]);
      p0 = fmaf(e0.x, qv[c].x, fmaf(e0.y, qv[c].y,
           fmaf(e0.z, qv[c].z, fmaf(e0.w, qv[c].w, p0))));
      p1 = fmaf(e1.x, qv[c].x, fmaf(e1.y, qv[c].y,
           fmaf(e1.z, qv[c].z, fmaf(e1.w, qv[c].w, p1))));
    }
#pragma unroll
    for (int off = 1; off < 8; off <<= 1) {
      p0 += __shfl_xor(p0, off);
      p1 += __shfl_xor(p1, off);
    }
    if (k == 0) {
      buf[b] = ((unsigned long long)fkey(p0) << 32) | (unsigned)(~(unsigned)id0);
      if (has1)
        buf[b1] = ((unsigned long long)fkey(p1) << 32) | (unsigned)(~(unsigned)id1);
    }
  }
  __syncthreads();

  // ---- flush ----
  if (tid == 0) sbase = atomicAdd(&cnt[q], (unsigned)nl);
  __syncthreads();
  const unsigned bp = sbase;
  for (int j = tid; j < nl; j += 256) {
    unsigned p = bp + (unsigned)j;
    if (p < CAPL) list[(size_t)q * CAPL + p] = buf[j];
  }
}

// ---------------------------------------------------------------------------
// Kernel FB: brute-force fallback for queries with cnt<Mm or overflow.
// ---------------------------------------------------------------------------
__global__ void fallback_kernel(const double* __restrict__ qv64,
                                const float* __restrict__ item,
                                const unsigned* __restrict__ qcp,
                                const unsigned* __restrict__ icodes,
                                unsigned* __restrict__ cnt,
                                unsigned long long* __restrict__ list) {
  const int q = blockIdx.x, tid = threadIdx.x;
  unsigned c = cnt[q];
  if (c >= (unsigned)Mm && c <= (unsigned)CAPL) return;

  __shared__ unsigned hist[NBINS];
  __shared__ float qf[256];
  __shared__ unsigned partial_[256];
  __shared__ int sbeta, scnt;

  qf[tid] = (float)qv64[(size_t)q * Ed + tid];
  for (int j = tid; j < NBINS; j += 256) hist[j] = 0u;
  if (tid == 0) scnt = 0;
  __syncthreads();

  const unsigned qc = qcp[q];
  for (int i = tid; i < Ni; i += 256) {
    float s = 0.0f;
    const float* er = item + (size_t)i * Ed;
    for (int e = 0; e < Ed; ++e) s = fmaf(qf[e], er[e], s);
    if (!anybyte_eq(qc, icodes[i])) s -= 1.0e6f;
    atomicAdd(&hist[fkey(s) >> 19], 1u);
  }
  __syncthreads();

  int beta = find_beta(hist, partial_, &sbeta, tid, Mm);
  __syncthreads();

  for (int i = tid; i < Ni; i += 256) {
    float s = 0.0f;
    const float* er = item + (size_t)i * Ed;
    for (int e = 0; e < Ed; ++e) s = fmaf(qf[e], er[e], s);
    if (!anybyte_eq(qc, icodes[i])) s -= 1.0e6f;
    unsigned kk = fkey(s);
    if ((int)(kk >> 19) >= beta) {
      int pos = atomicAdd(&scnt, 1);
      if (pos < CAPL)
        list[(size_t)q * CAPL + pos] =
            ((unsigned long long)kk << 32) | (unsigned)(~(unsigned)i);
    }
  }
  __syncthreads();
  if (tid == 0) cnt[q] = (unsigned)(scnt < CAPL ? scnt : CAPL);
}

// ---------------------------------------------------------------------------
// Kernel D: top-128 select from compact list (hist threshold + bitonic).
// ---------------------------------------------------------------------------
__global__ void select_kernel(const unsigned long long* __restrict__ list,
                              const unsigned* __restrict__ cnt,
                              unsigned* __restrict__ cand) {
  __shared__ unsigned long long buf[CAP2];   // 32 KB (aliased with hist)
  __shared__ unsigned partial_[256];
  __shared__ int sbeta, scnt;
  unsigned* hist = reinterpret_cast<unsigned*>(buf);

  const int q = blockIdx.x, tid = threadIdx.x;
  const unsigned long long* src = list + (size_t)q * CAPL;
  const int count = min((int)cnt[q], CAPL);

  for (int j = tid; j < NBINS; j += 256) hist[j] = 0u;
  if (tid == 0) scnt = 0;
  __syncthreads();

  for (int i = tid; i < count; i += 256)
    atomicAdd(&hist[(unsigned)(src[i] >> 32) >> 19], 1u);
  __syncthreads();

  int beta = find_beta(hist, partial_, &sbeta, tid, Mm);
  __syncthreads();   // hist dead; buf reuse begins

  for (int i = tid; i < count; i += 256) {
    unsigned long long v = src[i];
    if ((int)((unsigned)(v >> 32) >> 19) >= beta) {
      int pos = atomicAdd(&scnt, 1);
      if (pos < CAP2) buf[pos] = v;
    }
  }
  __syncthreads();

  int sc = min(scnt, CAP2);
  int n = Mm;
  while (n < sc) n <<= 1;
  for (int j = tid; j < n; j += 256)
    if (j >= sc) buf[j] = 0ull;
  __syncthreads();

  for (int k2 = 2; k2 <= n; k2 <<= 1) {
    for (int j = k2 >> 1; j > 0; j >>= 1) {
      for (int i = tid; i < n; i += 256) {
        int p = i ^ j;
        if (p > i) {
          bool up = ((i & k2) == 0);
          unsigned long long a = buf[i], b = buf[p];
          if ((a < b) == up) { buf[i] = b; buf[p] = a; }
        }
      }
      __syncthreads();
    }
  }

  if (tid < Mm)
    cand[q * Mm + tid] = ~(unsigned)(buf[tid] & 0xFFFFFFFFull);
}

// ---------------------------------------------------------------------------
// Kernel E: f64 re-rank of 128 candidates (wave-cooperative dots);
// sort (score desc, id asc); emit 100 ids (as f32) + gathered embeddings.
// ---------------------------------------------------------------------------
__global__ void rerank_kernel(const double* __restrict__ qv64,
                              const float* __restrict__ item,
                              const unsigned* __restrict__ qcp,
                              const unsigned* __restrict__ icodes,
                              const unsigned* __restrict__ cand,
                              float* __restrict__ out_ids,
                              float* __restrict__ out_emb) {
  const int q = blockIdx.x, tid = threadIdx.x;
  const int l = tid & 63, w = tid >> 6;
  __shared__ double qr[Ed];
  __shared__ double sc[Mm];
  __shared__ int sid[Mm];

  qr[tid] = qv64[(size_t)q * Ed + tid];
  if (tid < Mm) {
    int id = (int)cand[q * Mm + tid];
    if (id < 0 || id >= Ni) id = 0;
    sid[tid] = id;
  }
  __syncthreads();

  const unsigned qc = qcp[q];
  for (int cc = 0; cc < Mm / 4; ++cc) {
    const int ci = w * (Mm / 4) + cc;
    const int id = sid[ci];
    float4 ev = *reinterpret_cast<const float4*>(&item[(size_t)id * Ed + l * 4]);
    double p = fma((double)ev.x, qr[l * 4 + 0],
               fma((double)ev.y, qr[l * 4 + 1],
               fma((double)ev.z, qr[l * 4 + 2],
                   (double)ev.w * qr[l * 4 + 3])));
#pragma unroll
    for (int off = 32; off > 0; off >>= 1) p += __shfl_down(p, off);
    if (l == 0) {
      double s = p;
      if (!anybyte_eq(qc, icodes[id])) s -= 1.0e6;
      sc[ci] = s;
    }
  }
  __syncthreads();

  for (int k2 = 2; k2 <= Mm; k2 <<= 1) {
    for (int j = k2 >> 1; j > 0; j >>= 1) {
      for (int i = tid; i < Mm; i += 256) {
        int p = i ^ j;
        if (p > i) {
          bool up = ((i & k2) == 0);
          double sa = sc[i], sb = sc[p];
          int ia = sid[i], ib = sid[p];
          bool aAfterB = (sa < sb) || (sa == sb && ia > ib);
          if (aAfterB == up) {
            sc[i] = sb; sc[p] = sa;
            sid[i] = ib; sid[p] = ia;
          }
        }
      }
      __syncthreads();
    }
  }

  if (tid < Kk) out_ids[q * Kk + tid] = (float)sid[tid];
  for (int f = tid; f < Kk * 64; f += 256) {
    int r = f >> 6, c4 = f & 63;
    *reinterpret_cast<float4*>(&out_emb[((size_t)q * Kk + r) * Ed + c4 * 4]) =
        *reinterpret_cast<const float4*>(&item[(size_t)sid[r] * Ed + c4 * 4]);
  }
}

// ---------------------------------------------------------------------------
extern "C" void kernel_launch(void* const* d_in, const int* in_sizes, int n_in,
                              void* d_out, int out_size, void* d_ws, size_t ws_size,
                              hipStream_t stream) {
  const float* hidden = (const float*)d_in[0];
  const float* Wq     = (const float*)d_in[1];
  const float* bq     = (const float*)d_in[2];
  const float* gamma  = (const float*)d_in[3];
  const float* beta   = (const float*)d_in[4];
  const float* proj   = (const float*)d_in[5];
  const float* item   = (const float*)d_in[6];

  float* out = (float*)d_out;
  char* ws = (char*)d_ws;
  double*             qv64 = (double*)(ws + OFF_QV64);
  unsigned*           qcp  = (unsigned*)(ws + OFF_QC);
  unsigned*           ic   = (unsigned*)(ws + OFF_IC);
  unsigned*           cnt  = (unsigned*)(ws + OFF_CNT);
  unsigned*           cand = (unsigned*)(ws + OFF_CAND);
  unsigned long long* list = (unsigned long long*)(ws + OFF_LIST);
  double*             part = (double*)(ws + OFF_PART);

  qproj_gemm<<<dim3(QT, KC), dim3(256), 0, stream>>>(hidden, Wq, part);
  icode_kernel<<<dim3(Ni / IPB), dim3(256), 0, stream>>>(item, proj, ic);
  qproj_fin<<<dim3(Bq), dim3(256), 0, stream>>>(part, bq, gamma, beta, proj,
                                                out, qv64, qcp, cnt);
  score_kernel<<<dim3(Bq, NSLICE), dim3(256), 0, stream>>>(out, item, ic, qcp, cnt, list);
  fallback_kernel<<<dim3(Bq), dim3(256), 0, stream>>>(qv64, item, qcp, ic, cnt, list);
  select_kernel<<<dim3(Bq), dim3(256), 0, stream>>>(list, cnt, cand);
  rerank_kernel<<<dim3(Bq), dim3(256), 0, stream>>>(
      qv64, item, qcp, ic, cand,
      out + (size_t)Bq * Ed, out + (size_t)Bq * Ed + (size_t)Bq * Kk);
}

// Round 13
// 245.368 us; speedup vs baseline: 1.2052x; 1.2052x over previous
//
#include <hip/hip_runtime.h>
#include <math.h>

// Problem constants
#define Bq   256
#define Hd   2048
#define Ed   256
#define Ni   200000
#define Tt   4
#define NBITS 8
#define Kk   100
#define Mm   128            // rerank margin: top-128 by approx key superset of true top-100
#define CAPL 16384          // per-query compact candidate list capacity
#define CAPB 1024           // per-block LDS match buffer (slice expects ~48)
#define CAP2 4096           // select LDS collect capacity
#define NBINS 8192
#define NSLICE 64
#define ISLICE (Ni / NSLICE)   // 3125
#define NXCD 8
#define SPX (NSLICE / NXCD)    // 8 slices per XCD
#define IPB 64               // icode items per block (200000/64 = 3125 exact)
#define QPB 8                // qproj queries per block
#define QT  (Bq / QPB)       // 32 q-tiles
#define KC  16               // k-chunks
#define KCH (Hd / KC)        // 128

// ws layout (bytes) — total ~145.8 MB
#define OFF_QV64  0ull            // 256*256*8   = 524288
#define OFF_QC    524288ull       // 256*4       = 1024
#define OFF_IC    525312ull       // 200000*4    = 800000
#define OFF_CNT   1325312ull      // 256*4       = 1024
#define OFF_CAND  1326336ull      // 256*128*4   = 131072
#define OFF_LIST  103857408ull    // 256*16384*8  = 33554432
#define OFF_PART  137411840ull    // 16*256*256*8 = 8388608

__device__ __forceinline__ bool anybyte_eq(unsigned a, unsigned b) {
  unsigned x = a ^ b;
  return ((x - 0x01010101u) & ~x & 0x80808080u) != 0u;
}
__device__ __forceinline__ unsigned fkey(float s) {
  unsigned u = __float_as_uint(s);
  return (u & 0x80000000u) ? ~u : (u | 0x80000000u);
}

// histogram beta-find helper (shared across select/fallback)
__device__ __forceinline__ int find_beta(unsigned* hist, unsigned* partial_,
                                         int* sbeta, int tid, int target) {
  unsigned s = 0;
#pragma unroll 8
  for (int j = 0; j < 32; ++j) s += hist[tid * 32 + j];
  partial_[tid] = s;
  __syncthreads();
  if (tid == 0) {
    unsigned cum = 0;
    int c;
    for (c = 255; c > 0; --c) {
      if (cum + partial_[c] >= (unsigned)target) break;
      cum += partial_[c];
    }
    int b;
    for (b = c * 32 + 31; b > c * 32; --b) {
      if (cum + hist[b] >= (unsigned)target) break;
      cum += hist[b];
    }
    *sbeta = b;
  }
  __syncthreads();
  return *sbeta;
}

// ---------------------------------------------------------------------------
// Kernel A1: split-K f64 projection GEMM. grid (32 qtiles, 16 kchunks) x 256.
// ---------------------------------------------------------------------------
__global__ void __launch_bounds__(256) qproj_gemm(
    const float* __restrict__ hidden,
    const float* __restrict__ Wq,
    double* __restrict__ partial) {
  __shared__ float hs_t[KCH][QPB];   // [h][qq], 4 KB
  const int e = threadIdx.x;
  const int qbase = blockIdx.x * QPB;
  const int kc = blockIdx.y;

  for (int j = e; j < QPB * KCH; j += 256) {
    int qq = j >> 7, h = j & (KCH - 1);
    hs_t[h][qq] = hidden[(size_t)(qbase + qq) * Hd + kc * KCH + h];
  }
  __syncthreads();

  double acc[QPB];
#pragma unroll
  for (int qq = 0; qq < QPB; ++qq) acc[qq] = 0.0;

  for (int h = 0; h < KCH; ++h) {
    double w = (double)Wq[(size_t)(kc * KCH + h) * Ed + e];
    float4 ha = *reinterpret_cast<const float4*>(&hs_t[h][0]);
    float4 hb = *reinterpret_cast<const float4*>(&hs_t[h][4]);
    acc[0] = fma((double)ha.x, w, acc[0]);
    acc[1] = fma((double)ha.y, w, acc[1]);
    acc[2] = fma((double)ha.z, w, acc[2]);
    acc[3] = fma((double)ha.w, w, acc[3]);
    acc[4] = fma((double)hb.x, w, acc[4]);
    acc[5] = fma((double)hb.y, w, acc[5]);
    acc[6] = fma((double)hb.z, w, acc[6]);
    acc[7] = fma((double)hb.w, w, acc[7]);
  }

#pragma unroll
  for (int qq = 0; qq < QPB; ++qq)
    partial[((size_t)kc * Bq + qbase + qq) * Ed + e] = acc[qq];
}

// ---------------------------------------------------------------------------
// Kernel A2: finalize — sum 16 partials + LayerNorm + tanh + fused qcode.
// ---------------------------------------------------------------------------
__global__ void qproj_fin(const double* __restrict__ partial,
                          const float* __restrict__ bq,
                          const float* __restrict__ gamma,
                          const float* __restrict__ beta,
                          const float* __restrict__ proj,
                          float* __restrict__ out_qv,
                          double* __restrict__ qv64,
                          unsigned* __restrict__ qcp,
                          unsigned* __restrict__ cnt) {
  const int q = blockIdx.x, e = threadIdx.x;
  __shared__ double red[256];
  __shared__ double qd[256];
  __shared__ double s_mu, s_rs;

  if (e == 0) cnt[q] = 0u;

  double acc = 0.0;
#pragma unroll
  for (int kc = 0; kc < KC; ++kc)
    acc += partial[((size_t)kc * Bq + q) * Ed + e];
  acc += (double)bq[e];

  red[e] = acc;
  __syncthreads();
  for (int s = 128; s > 0; s >>= 1) {
    if (e < s) red[e] += red[e + s];
    __syncthreads();
  }
  if (e == 0) s_mu = red[0] / 256.0;
  __syncthreads();
  double d = acc - s_mu;
  red[e] = d * d;
  __syncthreads();
  for (int s = 128; s > 0; s >>= 1) {
    if (e < s) red[e] += red[e + s];
    __syncthreads();
  }
  if (e == 0) s_rs = 1.0 / sqrt(red[0] / 256.0 + 1e-5);
  __syncthreads();

  double y = (acc - s_mu) * s_rs * (double)gamma[e] + (double)beta[e];
  double t = tanh(y);
  out_qv[(size_t)q * Ed + e] = (float)t;
  qv64[(size_t)q * Ed + e] = t;
  qd[e] = t;
  __syncthreads();

  double dot = 0.0;
  if (e < 32) {
    const int tt = e >> 3, b = e & 7;
    const float* pp = proj + (size_t)tt * Ed * NBITS + b;
#pragma unroll 4
    for (int ee = 0; ee < Ed; ++ee)
      dot = fma(qd[ee], (double)pp[(size_t)ee * NBITS], dot);
  }
  unsigned long long mask = __ballot(e < 32 && dot > 0.0);
  if (e == 0) qcp[q] = (unsigned)mask;
}

// ---------------------------------------------------------------------------
// Kernel I (v9): f32 LDS tile, wave-uniform table -> proj in SGPRs.
// grid 3125 x 256. Tile [64][65] f32, 16.6 KB -> 8 blocks/CU.
// f32 accumulate, thr 2e-4, per-bit f64 recompute (R4-R6 proven exact).
// ---------------------------------------------------------------------------
__global__ void __launch_bounds__(256) icode_kernel(
    const float* __restrict__ item,
    const float* __restrict__ proj,
    unsigned* __restrict__ icodes) {
  __shared__ float ts[IPB * 65];       // 16640 B
  __shared__ unsigned icode_s[IPB];
  const int tid = threadIdx.x;
  const int base = blockIdx.x * IPB;
  const int il = tid & 63;
  const int t = __builtin_amdgcn_readfirstlane(tid >> 6);
  const float* pt = proj + (size_t)t * (Ed * NBITS);   // [e][8]

  if (tid < IPB) icode_s[tid] = 0u;

  float acc[8];
#pragma unroll
  for (int b = 0; b < 8; ++b) acc[b] = 0.0f;

  for (int c = 0; c < 4; ++c) {        // 4 chunks of 64 e
    __syncthreads();
#pragma unroll
    for (int rep = 0; rep < 16; ++rep) {
      const int fi = rep * 256 + tid;
      const int row = fi >> 6, e = fi & 63;
      ts[row * 65 + e] = item[(size_t)(base + row) * Ed + c * 64 + e];
    }
    __syncthreads();

#pragma unroll 8
    for (int e = 0; e < 64; ++e) {
      const float av = ts[il * 65 + e];
      const float4 pa = *reinterpret_cast<const float4*>(&pt[(size_t)(c * 64 + e) * 8]);
      const float4 pb = *reinterpret_cast<const float4*>(&pt[(size_t)(c * 64 + e) * 8 + 4]);
      acc[0] = fmaf(av, pa.x, acc[0]);
      acc[1] = fmaf(av, pa.y, acc[1]);
      acc[2] = fmaf(av, pa.z, acc[2]);
      acc[3] = fmaf(av, pa.w, acc[3]);
      acc[4] = fmaf(av, pb.x, acc[4]);
      acc[5] = fmaf(av, pb.y, acc[5]);
      acc[6] = fmaf(av, pb.z, acc[6]);
      acc[7] = fmaf(av, pb.w, acc[7]);
    }
  }

  unsigned byte = 0, bl = 0;
#pragma unroll
  for (int b = 0; b < 8; ++b) {
    byte |= (acc[b] > 0.0f ? 1u : 0u) << b;
    bl |= (fabsf(acc[b]) < 2e-4f ? 1u : 0u) << b;
  }

  if (bl) {   // rare exact f64 path (~0.016% of bits)
    const int gi = base + il;
    const float* er = item + (size_t)gi * Ed;
    while (bl) {
      const int b = __builtin_ctz(bl);
      bl &= bl - 1;
      const float* pp = pt + b;
      double a = 0.0;
      for (int e2 = 0; e2 < Ed; ++e2)
        a = fma((double)er[e2], (double)pp[(size_t)e2 * NBITS], a);
      if (a > 0.0) byte |= 1u << b; else byte &= ~(1u << b);
    }
  }

  atomicOr(&icode_s[il], byte << (8 * t));
  __syncthreads();
  if (tid < IPB) icodes[base + tid] = icode_s[tid];
}

// ---------------------------------------------------------------------------
// Kernel F (v4): v3 + XCD-locality slicing. 1-D grid 16384, in-kernel decode:
// xcd = lin&7, rank = lin>>3, sl = xcd*8 + (rank>>8), q = rank&255.
// NSLICE=64 -> slice footprint 3.1 MB < 4 MB L2; all 256 q-blocks of a slice
// land consecutively on ONE XCD -> gathers L2-hit after first touch.
// Scan: ballot + ranked parallel append. Process: 32 x 8-lane groups,
// unroll-2 dual-dot. Flush: ONE global atomic + coalesced.
// ---------------------------------------------------------------------------
__global__ void __launch_bounds__(256) score_kernel(
    const float* __restrict__ qvf,
    const float* __restrict__ item,
    const unsigned* __restrict__ icodes,
    const unsigned* __restrict__ qcp,
    unsigned* __restrict__ cnt,
    unsigned long long* __restrict__ list) {
  __shared__ unsigned long long buf[CAPB];   // 8 KB: ids, then (key|~id)
  __shared__ int lcnt;
  __shared__ unsigned sbase;

  const int tid = threadIdx.x;
  const int lin = blockIdx.x;
  const int xcd = lin & (NXCD - 1);
  const int rank = lin >> 3;
  const int sl = xcd * SPX + (rank >> 8);
  const int q = rank & 255;
  const int l = tid & 63, wid = tid >> 6;
  const int k = tid & 7;             // lane within 8-group
  const int gg = tid >> 3;           // group id 0..31

  if (tid == 0) lcnt = 0;
  const unsigned qc = qcp[q];

  // per-thread qv fragment: elements (c*8+k)*4 .. +4, c = 0..7 (32 VGPR)
  float4 qv[8];
#pragma unroll
  for (int c = 0; c < 8; ++c)
    qv[c] = *reinterpret_cast<const float4*>(&qvf[(size_t)q * Ed + (c * 8 + k) * 4]);
  __syncthreads();

  // ---- scan phase: ballot + ranked parallel append ----
  const int i0 = sl * ISLICE, i1 = i0 + ISLICE;
  for (int bse = i0 + wid * 64; bse < i1; bse += 256) {
    const int i = bse + l;
    bool m = (i < i1) && anybyte_eq(qc, icodes[i]);
    unsigned long long mask = __ballot(m);
    if (mask) {
      int base_ = 0;
      if (l == 0) base_ = atomicAdd(&lcnt, __popcll(mask));
      base_ = __shfl(base_, 0);
      if (m) {
        int rnk = __popcll(mask & ((1ull << l) - 1ull));
        int pos = base_ + rnk;
        if (pos < CAPB) buf[pos] = (unsigned long long)(unsigned)i;
      }
    }
  }
  __syncthreads();

  if (lcnt > CAPB) {   // overflow: force brute-force fallback for q
    if (tid == 0) atomicAdd(&cnt[q], (unsigned)(CAPL + 1));
    return;
  }
  const int nl = lcnt;

  // ---- process phase: 32 groups x dual-dot pipeline ----
  for (int b = gg; b < nl; b += 64) {
    const int b1 = b + 32;
    const bool has1 = (b1 < nl);
    const int id0 = (int)(unsigned)buf[b];
    const int id1 = has1 ? (int)(unsigned)buf[b1] : id0;
    const float* r0 = item + (size_t)id0 * Ed;
    const float* r1 = item + (size_t)id1 * Ed;
    float p0 = 0.0f, p1 = 0.0f;
#pragma unroll
    for (int c = 0; c < 8; ++c) {
      const float4 e0 = *reinterpret_cast<const float4*>(&r0[(c * 8 + k) * 4]);
      const float4 e1 = *reinterpret_cast<const float4*>(&r1[(c * 8 + k) * 4]);
      p0 = fmaf(e0.x, qv[c].x, fmaf(e0.y, qv[c].y,
           fmaf(e0.z, qv[c].z, fmaf(e0.w, qv[c].w, p0))));
      p1 = fmaf(e1.x, qv[c].x, fmaf(e1.y, qv[c].y,
           fmaf(e1.z, qv[c].z, fmaf(e1.w, qv[c].w, p1))));
    }
#pragma unroll
    for (int off = 1; off < 8; off <<= 1) {
      p0 += __shfl_xor(p0, off);
      p1 += __shfl_xor(p1, off);
    }
    if (k == 0) {
      buf[b] = ((unsigned long long)fkey(p0) << 32) | (unsigned)(~(unsigned)id0);
      if (has1)
        buf[b1] = ((unsigned long long)fkey(p1) << 32) | (unsigned)(~(unsigned)id1);
    }
  }
  __syncthreads();

  // ---- flush ----
  if (tid == 0) sbase = atomicAdd(&cnt[q], (unsigned)nl);
  __syncthreads();
  const unsigned bp = sbase;
  for (int j = tid; j < nl; j += 256) {
    unsigned p = bp + (unsigned)j;
    if (p < CAPL) list[(size_t)q * CAPL + p] = buf[j];
  }
}

// ---------------------------------------------------------------------------
// Kernel FB: brute-force fallback for queries with cnt<Mm or overflow.
// ---------------------------------------------------------------------------
__global__ void fallback_kernel(const double* __restrict__ qv64,
                                const float* __restrict__ item,
                                const unsigned* __restrict__ qcp,
                                const unsigned* __restrict__ icodes,
                                unsigned* __restrict__ cnt,
                                unsigned long long* __restrict__ list) {
  const int q = blockIdx.x, tid = threadIdx.x;
  unsigned c = cnt[q];
  if (c >= (unsigned)Mm && c <= (unsigned)CAPL) return;

  __shared__ unsigned hist[NBINS];
  __shared__ float qf[256];
  __shared__ unsigned partial_[256];
  __shared__ int sbeta, scnt;

  qf[tid] = (float)qv64[(size_t)q * Ed + tid];
  for (int j = tid; j < NBINS; j += 256) hist[j] = 0u;
  if (tid == 0) scnt = 0;
  __syncthreads();

  const unsigned qc = qcp[q];
  for (int i = tid; i < Ni; i += 256) {
    float s = 0.0f;
    const float* er = item + (size_t)i * Ed;
    for (int e = 0; e < Ed; ++e) s = fmaf(qf[e], er[e], s);
    if (!anybyte_eq(qc, icodes[i])) s -= 1.0e6f;
    atomicAdd(&hist[fkey(s) >> 19], 1u);
  }
  __syncthreads();

  int beta = find_beta(hist, partial_, &sbeta, tid, Mm);
  __syncthreads();

  for (int i = tid; i < Ni; i += 256) {
    float s = 0.0f;
    const float* er = item + (size_t)i * Ed;
    for (int e = 0; e < Ed; ++e) s = fmaf(qf[e], er[e], s);
    if (!anybyte_eq(qc, icodes[i])) s -= 1.0e6f;
    unsigned kk = fkey(s);
    if ((int)(kk >> 19) >= beta) {
      int pos = atomicAdd(&scnt, 1);
      if (pos < CAPL)
        list[(size_t)q * CAPL + pos] =
            ((unsigned long long)kk << 32) | (unsigned)(~(unsigned)i);
    }
  }
  __syncthreads();
  if (tid == 0) cnt[q] = (unsigned)(scnt < CAPL ? scnt : CAPL);
}

// ---------------------------------------------------------------------------
// Kernel D: top-128 select from compact list (hist threshold + bitonic).
// ---------------------------------------------------------------------------
__global__ void select_kernel(const unsigned long long* __restrict__ list,
                              const unsigned* __restrict__ cnt,
                              unsigned* __restrict__ cand) {
  __shared__ unsigned long long buf[CAP2];   // 32 KB (aliased with hist)
  __shared__ unsigned partial_[256];
  __shared__ int sbeta, scnt;
  unsigned* hist = reinterpret_cast<unsigned*>(buf);

  const int q = blockIdx.x, tid = threadIdx.x;
  const unsigned long long* src = list + (size_t)q * CAPL;
  const int count = min((int)cnt[q], CAPL);

  for (int j = tid; j < NBINS; j += 256) hist[j] = 0u;
  if (tid == 0) scnt = 0;
  __syncthreads();

  for (int i = tid; i < count; i += 256)
    atomicAdd(&hist[(unsigned)(src[i] >> 32) >> 19], 1u);
  __syncthreads();

  int beta = find_beta(hist, partial_, &sbeta, tid, Mm);
  __syncthreads();   // hist dead; buf reuse begins

  for (int i = tid; i < count; i += 256) {
    unsigned long long v = src[i];
    if ((int)((unsigned)(v >> 32) >> 19) >= beta) {
      int pos = atomicAdd(&scnt, 1);
      if (pos < CAP2) buf[pos] = v;
    }
  }
  __syncthreads();

  int sc = min(scnt, CAP2);
  int n = Mm;
  while (n < sc) n <<= 1;
  for (int j = tid; j < n; j += 256)
    if (j >= sc) buf[j] = 0ull;
  __syncthreads();

  for (int k2 = 2; k2 <= n; k2 <<= 1) {
    for (int j = k2 >> 1; j > 0; j >>= 1) {
      for (int i = tid; i < n; i += 256) {
        int p = i ^ j;
        if (p > i) {
          bool up = ((i & k2) == 0);
          unsigned long long a = buf[i], b = buf[p];
          if ((a < b) == up) { buf[i] = b; buf[p] = a; }
        }
      }
      __syncthreads();
    }
  }

  if (tid < Mm)
    cand[q * Mm + tid] = ~(unsigned)(buf[tid] & 0xFFFFFFFFull);
}

// ---------------------------------------------------------------------------
// Kernel E: f64 re-rank of 128 candidates (wave-cooperative dots);
// sort (score desc, id asc); emit 100 ids (as f32) + gathered embeddings.
// ---------------------------------------------------------------------------
__global__ void rerank_kernel(const double* __restrict__ qv64,
                              const float* __restrict__ item,
                              const unsigned* __restrict__ qcp,
                              const unsigned* __restrict__ icodes,
                              const unsigned* __restrict__ cand,
                              float* __restrict__ out_ids,
                              float* __restrict__ out_emb) {
  const int q = blockIdx.x, tid = threadIdx.x;
  const int l = tid & 63, w = tid >> 6;
  __shared__ double qr[Ed];
  __shared__ double sc[Mm];
  __shared__ int sid[Mm];

  qr[tid] = qv64[(size_t)q * Ed + tid];
  if (tid < Mm) {
    int id = (int)cand[q * Mm + tid];
    if (id < 0 || id >= Ni) id = 0;
    sid[tid] = id;
  }
  __syncthreads();

  const unsigned qc = qcp[q];
  for (int cc = 0; cc < Mm / 4; ++cc) {
    const int ci = w * (Mm / 4) + cc;
    const int id = sid[ci];
    float4 ev = *reinterpret_cast<const float4*>(&item[(size_t)id * Ed + l * 4]);
    double p = fma((double)ev.x, qr[l * 4 + 0],
               fma((double)ev.y, qr[l * 4 + 1],
               fma((double)ev.z, qr[l * 4 + 2],
                   (double)ev.w * qr[l * 4 + 3])));
#pragma unroll
    for (int off = 32; off > 0; off >>= 1) p += __shfl_down(p, off);
    if (l == 0) {
      double s = p;
      if (!anybyte_eq(qc, icodes[id])) s -= 1.0e6;
      sc[ci] = s;
    }
  }
  __syncthreads();

  for (int k2 = 2; k2 <= Mm; k2 <<= 1) {
    for (int j = k2 >> 1; j > 0; j >>= 1) {
      for (int i = tid; i < Mm; i += 256) {
        int p = i ^ j;
        if (p > i) {
          bool up = ((i & k2) == 0);
          double sa = sc[i], sb = sc[p];
          int ia = sid[i], ib = sid[p];
          bool aAfterB = (sa < sb) || (sa == sb && ia > ib);
          if (aAfterB == up) {
            sc[i] = sb; sc[p] = sa;
            sid[i] = ib; sid[p] = ia;
          }
        }
      }
      __syncthreads();
    }
  }

  if (tid < Kk) out_ids[q * Kk + tid] = (float)sid[tid];
  for (int f = tid; f < Kk * 64; f += 256) {
    int r = f >> 6, c4 = f & 63;
    *reinterpret_cast<float4*>(&out_emb[((size_t)q * Kk + r) * Ed + c4 * 4]) =
        *reinterpret_cast<const float4*>(&item[(size_t)sid[r] * Ed + c4 * 4]);
  }
}

// ---------------------------------------------------------------------------
extern "C" void kernel_launch(void* const* d_in, const int* in_sizes, int n_in,
                              void* d_out, int out_size, void* d_ws, size_t ws_size,
                              hipStream_t stream) {
  const float* hidden = (const float*)d_in[0];
  const float* Wq     = (const float*)d_in[1];
  const float* bq     = (const float*)d_in[2];
  const float* gamma  = (const float*)d_in[3];
  const float* beta   = (const float*)d_in[4];
  const float* proj   = (const float*)d_in[5];
  const float* item   = (const float*)d_in[6];

  float* out = (float*)d_out;
  char* ws = (char*)d_ws;
  double*             qv64 = (double*)(ws + OFF_QV64);
  unsigned*           qcp  = (unsigned*)(ws + OFF_QC);
  unsigned*           ic   = (unsigned*)(ws + OFF_IC);
  unsigned*           cnt  = (unsigned*)(ws + OFF_CNT);
  unsigned*           cand = (unsigned*)(ws + OFF_CAND);
  unsigned long long* list = (unsigned long long*)(ws + OFF_LIST);
  double*             part = (double*)(ws + OFF_PART);

  qproj_gemm<<<dim3(QT, KC), dim3(256), 0, stream>>>(hidden, Wq, part);
  icode_kernel<<<dim3(Ni / IPB), dim3(256), 0, stream>>>(item, proj, ic);
  qproj_fin<<<dim3(Bq), dim3(256), 0, stream>>>(part, bq, gamma, beta, proj,
                                                out, qv64, qcp, cnt);
  score_kernel<<<dim3(Bq * NSLICE), dim3(256), 0, stream>>>(out, item, ic, qcp, cnt, list);
  fallback_kernel<<<dim3(Bq), dim3(256), 0, stream>>>(qv64, item, qcp, ic, cnt, list);
  select_kernel<<<dim3(Bq), dim3(256), 0, stream>>>(list, cnt, cand);
  rerank_kernel<<<dim3(Bq), dim3(256), 0, stream>>>(
      qv64, item, qcp, ic, cand,
      out + (size_t)Bq * Ed, out + (size_t)Bq * Ed + (size_t)Bq * Kk);
}

// Round 14
// 203.059 us; speedup vs baseline: 1.4563x; 1.2084x over previous
//
#include <hip/hip_runtime.h>
#include <math.h>

// Problem constants
#define Bq   256
#define Hd   2048
#define Ed   256
#define Ni   200000
#define Tt   4
#define NBITS 8
#define Kk   100
#define Mm   128            // rerank margin: top-128 by approx key superset of true top-100
#define CAPL 16384          // per-query compact candidate list capacity
#define CAPB2 512           // per-(block,q) expected ~48; unified buf = QPS*CAPB2
#define CAP2 4096           // select LDS collect capacity
#define NBINS 8192
#define NSLICE 64
#define ISLICE (Ni / NSLICE)   // 3125
#define NXCD 8
#define SPX (NSLICE / NXCD)    // 8 slices per XCD
#define QPS 4                // score queries per block
#define IPB 64               // icode items per block (200000/64 = 3125 exact)
#define QPB 8                // qproj queries per block
#define QT  (Bq / QPB)       // 32 q-tiles
#define KC  16               // k-chunks
#define KCH (Hd / KC)        // 128

// ws layout (bytes) — total ~145.8 MB
#define OFF_QV64  0ull            // 256*256*8   = 524288
#define OFF_QC    524288ull       // 256*4       = 1024
#define OFF_IC    525312ull       // 200000*4    = 800000
#define OFF_CNT   1325312ull      // 256*4       = 1024
#define OFF_LIST  103857408ull    // 256*16384*8  = 33554432
#define OFF_PART  137411840ull    // 16*256*256*8 = 8388608

__device__ __forceinline__ bool anybyte_eq(unsigned a, unsigned b) {
  unsigned x = a ^ b;
  return ((x - 0x01010101u) & ~x & 0x80808080u) != 0u;
}
__device__ __forceinline__ unsigned fkey(float s) {
  unsigned u = __float_as_uint(s);
  return (u & 0x80000000u) ? ~u : (u | 0x80000000u);
}

// histogram beta-find helper
__device__ __forceinline__ int find_beta(unsigned* hist, unsigned* partial_,
                                         int* sbeta, int tid, int target) {
  unsigned s = 0;
#pragma unroll 8
  for (int j = 0; j < 32; ++j) s += hist[tid * 32 + j];
  partial_[tid] = s;
  __syncthreads();
  if (tid == 0) {
    unsigned cum = 0;
    int c;
    for (c = 255; c > 0; --c) {
      if (cum + partial_[c] >= (unsigned)target) break;
      cum += partial_[c];
    }
    int b;
    for (b = c * 32 + 31; b > c * 32; --b) {
      if (cum + hist[b] >= (unsigned)target) break;
      cum += hist[b];
    }
    *sbeta = b;
  }
  __syncthreads();
  return *sbeta;
}

// ---------------------------------------------------------------------------
// Kernel A1+I fused: blocks [0, 512) = split-K f64 qproj GEMM;
// blocks [512, 3637) = icode v9 (f32 LDS tile, wave-uniform table).
// Shared 16.6 KB smem reused by both branches. Overlaps memory-bound icode
// with f64-VALU-bound qproj.
// ---------------------------------------------------------------------------
__global__ void __launch_bounds__(256) qp_icode_kernel(
    const float* __restrict__ hidden,
    const float* __restrict__ Wq,
    double* __restrict__ partial,
    const float* __restrict__ item,
    const float* __restrict__ proj,
    unsigned* __restrict__ icodes) {
  __shared__ float smem[IPB * 65];     // 16640 B
  __shared__ unsigned icode_s[IPB];
  const int blk = blockIdx.x;
  const int tid = threadIdx.x;

  if (blk < QT * KC) {
    // ---- qproj_gemm branch (proven R6) ----
    float (*hs_t)[QPB] = reinterpret_cast<float (*)[QPB]>(smem);
    const int e = tid;
    const int qbase = (blk & (QT - 1)) * QPB;
    const int kc = blk >> 5;

    for (int j = e; j < QPB * KCH; j += 256) {
      int qq = j >> 7, h = j & (KCH - 1);
      hs_t[h][qq] = hidden[(size_t)(qbase + qq) * Hd + kc * KCH + h];
    }
    __syncthreads();

    double acc[QPB];
#pragma unroll
    for (int qq = 0; qq < QPB; ++qq) acc[qq] = 0.0;

    for (int h = 0; h < KCH; ++h) {
      double w = (double)Wq[(size_t)(kc * KCH + h) * Ed + e];
      float4 ha = *reinterpret_cast<const float4*>(&hs_t[h][0]);
      float4 hb = *reinterpret_cast<const float4*>(&hs_t[h][4]);
      acc[0] = fma((double)ha.x, w, acc[0]);
      acc[1] = fma((double)ha.y, w, acc[1]);
      acc[2] = fma((double)ha.z, w, acc[2]);
      acc[3] = fma((double)ha.w, w, acc[3]);
      acc[4] = fma((double)hb.x, w, acc[4]);
      acc[5] = fma((double)hb.y, w, acc[5]);
      acc[6] = fma((double)hb.z, w, acc[6]);
      acc[7] = fma((double)hb.w, w, acc[7]);
    }

#pragma unroll
    for (int qq = 0; qq < QPB; ++qq)
      partial[((size_t)kc * Bq + qbase + qq) * Ed + e] = acc[qq];
    return;
  }

  // ---- icode branch (proven R10 v8/v9) ----
  const int base = (blk - QT * KC) * IPB;
  const int il = tid & 63;
  const int t = __builtin_amdgcn_readfirstlane(tid >> 6);
  const float* pt = proj + (size_t)t * (Ed * NBITS);   // [e][8]

  if (tid < IPB) icode_s[tid] = 0u;

  float acc[8];
#pragma unroll
  for (int b = 0; b < 8; ++b) acc[b] = 0.0f;

  for (int c = 0; c < 4; ++c) {        // 4 chunks of 64 e
    __syncthreads();
#pragma unroll
    for (int rep = 0; rep < 16; ++rep) {
      const int fi = rep * 256 + tid;
      const int row = fi >> 6, e = fi & 63;
      smem[row * 65 + e] = item[(size_t)(base + row) * Ed + c * 64 + e];
    }
    __syncthreads();

#pragma unroll 8
    for (int e = 0; e < 64; ++e) {
      const float av = smem[il * 65 + e];
      const float4 pa = *reinterpret_cast<const float4*>(&pt[(size_t)(c * 64 + e) * 8]);
      const float4 pb = *reinterpret_cast<const float4*>(&pt[(size_t)(c * 64 + e) * 8 + 4]);
      acc[0] = fmaf(av, pa.x, acc[0]);
      acc[1] = fmaf(av, pa.y, acc[1]);
      acc[2] = fmaf(av, pa.z, acc[2]);
      acc[3] = fmaf(av, pa.w, acc[3]);
      acc[4] = fmaf(av, pb.x, acc[4]);
      acc[5] = fmaf(av, pb.y, acc[5]);
      acc[6] = fmaf(av, pb.z, acc[6]);
      acc[7] = fmaf(av, pb.w, acc[7]);
    }
  }

  unsigned byte = 0, bl = 0;
#pragma unroll
  for (int b = 0; b < 8; ++b) {
    byte |= (acc[b] > 0.0f ? 1u : 0u) << b;
    bl |= (fabsf(acc[b]) < 2e-4f ? 1u : 0u) << b;
  }

  if (bl) {   // rare exact f64 path (~0.016% of bits)
    const int gi = base + il;
    const float* er = item + (size_t)gi * Ed;
    while (bl) {
      const int b = __builtin_ctz(bl);
      bl &= bl - 1;
      const float* pp = pt + b;
      double a = 0.0;
      for (int e2 = 0; e2 < Ed; ++e2)
        a = fma((double)er[e2], (double)pp[(size_t)e2 * NBITS], a);
      if (a > 0.0) byte |= 1u << b; else byte &= ~(1u << b);
    }
  }

  atomicOr(&icode_s[il], byte << (8 * t));
  __syncthreads();
  if (tid < IPB) icodes[base + tid] = icode_s[tid];
}

// ---------------------------------------------------------------------------
// Kernel A2: finalize — sum 16 partials + LayerNorm + tanh + fused qcode.
// Also zeroes cnt (must run before score).
// ---------------------------------------------------------------------------
__global__ void qproj_fin(const double* __restrict__ partial,
                          const float* __restrict__ bq,
                          const float* __restrict__ gamma,
                          const float* __restrict__ beta,
                          const float* __restrict__ proj,
                          float* __restrict__ out_qv,
                          double* __restrict__ qv64,
                          unsigned* __restrict__ qcp,
                          unsigned* __restrict__ cnt) {
  const int q = blockIdx.x, e = threadIdx.x;
  __shared__ double red[256];
  __shared__ double qd[256];
  __shared__ double s_mu, s_rs;

  if (e == 0) cnt[q] = 0u;

  double acc = 0.0;
#pragma unroll
  for (int kc = 0; kc < KC; ++kc)
    acc += partial[((size_t)kc * Bq + q) * Ed + e];
  acc += (double)bq[e];

  red[e] = acc;
  __syncthreads();
  for (int s = 128; s > 0; s >>= 1) {
    if (e < s) red[e] += red[e + s];
    __syncthreads();
  }
  if (e == 0) s_mu = red[0] / 256.0;
  __syncthreads();
  double d = acc - s_mu;
  red[e] = d * d;
  __syncthreads();
  for (int s = 128; s > 0; s >>= 1) {
    if (e < s) red[e] += red[e + s];
    __syncthreads();
  }
  if (e == 0) s_rs = 1.0 / sqrt(red[0] / 256.0 + 1e-5);
  __syncthreads();

  double y = (acc - s_mu) * s_rs * (double)gamma[e] + (double)beta[e];
  double t = tanh(y);
  out_qv[(size_t)q * Ed + e] = (float)t;
  qv64[(size_t)q * Ed + e] = t;
  qd[e] = t;
  __syncthreads();

  double dot = 0.0;
  if (e < 32) {
    const int tt = e >> 3, b = e & 7;
    const float* pp = proj + (size_t)tt * Ed * NBITS + b;
#pragma unroll 4
    for (int ee = 0; ee < Ed; ++ee)
      dot = fma(qd[ee], (double)pp[(size_t)ee * NBITS], dot);
  }
  unsigned long long mask = __ballot(e < 32 && dot > 0.0);
  if (e == 0) qcp[q] = (unsigned)mask;
}

// ---------------------------------------------------------------------------
// Kernel F (v5): QPS=4 queries per block; one icode scan serves 4 queries.
// grid 4096 = NSLICE x (Bq/QPS), XCD-decode keeps slice on one XCD (R13).
// Scan: 4 ballots/chunk -> unified LDS queue (id + qi byte). Process: 32 x
// 8-lane groups dual-dot, qv from LDS. Flush: 2-pass LDS count -> 4 atomics.
// ---------------------------------------------------------------------------
__global__ void __launch_bounds__(256) score_kernel(
    const float* __restrict__ qvf,
    const float* __restrict__ item,
    const unsigned* __restrict__ icodes,
    const unsigned* __restrict__ qcp,
    unsigned* __restrict__ cnt,
    unsigned long long* __restrict__ list) {
  __shared__ unsigned long long buf[QPS * CAPB2];   // 16 KB
  __shared__ unsigned char qibuf[QPS * CAPB2];      // 2 KB
  __shared__ float qvs[QPS][Ed];                    // 4 KB
  __shared__ int lcnt;
  __shared__ unsigned ccnt[QPS], fcnt[QPS], sbase_s[QPS];

  const int tid = threadIdx.x;
  const int lin = blockIdx.x;
  const int xcd = lin & (NXCD - 1);
  const int rank = lin >> 3;               // 0..511
  const int sl = xcd * SPX + (rank >> 6);  // slice
  const int q0 = (rank & 63) * QPS;
  const int l = tid & 63, wid = tid >> 6;
  const int k = tid & 7;                   // lane within 8-group
  const int gg = tid >> 3;                 // group id 0..31

  if (tid == 0) lcnt = 0;
  if (tid < QPS) { ccnt[tid] = 0u; fcnt[tid] = 0u; }

  unsigned qc[QPS];
#pragma unroll
  for (int qi = 0; qi < QPS; ++qi) qc[qi] = qcp[q0 + qi];

  for (int j = tid; j < QPS * (Ed / 4); j += 256) {
    int qi = j >> 6, c4 = j & 63;
    *reinterpret_cast<float4*>(&qvs[qi][c4 * 4]) =
        *reinterpret_cast<const float4*>(&qvf[(size_t)(q0 + qi) * Ed + c4 * 4]);
  }
  __syncthreads();

  // ---- scan ----
  const int i0 = sl * ISLICE, i1 = i0 + ISLICE;
  for (int bse = i0 + wid * 64; bse < i1; bse += 256) {
    const int i = bse + l;
    const bool iv = (i < i1);
    const unsigned code = iv ? icodes[i] : 0u;
#pragma unroll
    for (int qi = 0; qi < QPS; ++qi) {
      bool m = iv && anybyte_eq(qc[qi], code);
      unsigned long long mask = __ballot(m);
      if (mask) {
        int base_ = 0;
        if (l == 0) base_ = atomicAdd(&lcnt, __popcll(mask));
        base_ = __shfl(base_, 0);
        if (m) {
          int rnk = __popcll(mask & ((1ull << l) - 1ull));
          int pos = base_ + rnk;
          if (pos < QPS * CAPB2) {
            buf[pos] = (unsigned long long)(unsigned)i;
            qibuf[pos] = (unsigned char)qi;
          }
        }
      }
    }
  }
  __syncthreads();

  if (lcnt > QPS * CAPB2) {   // overflow: fallback for all 4 queries
    if (tid < QPS) atomicAdd(&cnt[q0 + tid], (unsigned)(CAPL + 1));
    return;
  }
  const int nl = lcnt;

  // ---- process: 32 groups x dual-dot, qv from LDS ----
  for (int b = gg; b < nl; b += 64) {
    const int b1 = b + 32;
    const bool has1 = (b1 < nl);
    const int id0 = (int)(unsigned)buf[b];
    const int qi0 = qibuf[b];
    const int id1 = has1 ? (int)(unsigned)buf[b1] : id0;
    const int qi1 = has1 ? qibuf[b1] : qi0;
    const float* r0 = item + (size_t)id0 * Ed;
    const float* r1 = item + (size_t)id1 * Ed;
    float p0 = 0.0f, p1 = 0.0f;
#pragma unroll
    for (int c = 0; c < 8; ++c) {
      const float4 e0 = *reinterpret_cast<const float4*>(&r0[(c * 8 + k) * 4]);
      const float4 qa = *reinterpret_cast<const float4*>(&qvs[qi0][(c * 8 + k) * 4]);
      const float4 e1 = *reinterpret_cast<const float4*>(&r1[(c * 8 + k) * 4]);
      const float4 qb = *reinterpret_cast<const float4*>(&qvs[qi1][(c * 8 + k) * 4]);
      p0 = fmaf(e0.x, qa.x, fmaf(e0.y, qa.y,
           fmaf(e0.z, qa.z, fmaf(e0.w, qa.w, p0))));
      p1 = fmaf(e1.x, qb.x, fmaf(e1.y, qb.y,
           fmaf(e1.z, qb.z, fmaf(e1.w, qb.w, p1))));
    }
#pragma unroll
    for (int off = 1; off < 8; off <<= 1) {
      p0 += __shfl_xor(p0, off);
      p1 += __shfl_xor(p1, off);
    }
    if (k == 0) {
      buf[b] = ((unsigned long long)fkey(p0) << 32) | (unsigned)(~(unsigned)id0);
      if (has1)
        buf[b1] = ((unsigned long long)fkey(p1) << 32) | (unsigned)(~(unsigned)id1);
    }
  }
  __syncthreads();

  // ---- flush: count per qi, reserve, scatter ----
  for (int j = tid; j < nl; j += 256) atomicAdd(&ccnt[qibuf[j]], 1u);
  __syncthreads();
  if (tid < QPS) sbase_s[tid] = atomicAdd(&cnt[q0 + tid], ccnt[tid]);
  __syncthreads();
  for (int j = tid; j < nl; j += 256) {
    const int qi = qibuf[j];
    unsigned pos = sbase_s[qi] + atomicAdd(&fcnt[qi], 1u);
    if (pos < CAPL) list[(size_t)(q0 + qi) * CAPL + pos] = buf[j];
  }
}

// ---------------------------------------------------------------------------
// Kernel D+FB+E fused: per-q block. If cnt out-of-range, brute-force rebuild
// (hist aliases buf; never expected). Then top-128 select (hist + bitonic),
// then f64 rerank + sort + emit, cand passed through LDS.
// ---------------------------------------------------------------------------
__global__ void selrerank_kernel(unsigned long long* __restrict__ list,
                                 const unsigned* __restrict__ cnt,
                                 const double* __restrict__ qv64,
                                 const float* __restrict__ item,
                                 const unsigned* __restrict__ qcp,
                                 const unsigned* __restrict__ icodes,
                                 float* __restrict__ out_ids,
                                 float* __restrict__ out_emb) {
  __shared__ unsigned long long buf[CAP2];   // 32 KB (aliased as hist)
  __shared__ unsigned partial_[256];
  __shared__ int sbeta, scnt;
  __shared__ double qr[Ed];                  // 2 KB
  __shared__ float qf[256];
  __shared__ double sc[Mm];
  __shared__ int sid[Mm];
  unsigned* hist = reinterpret_cast<unsigned*>(buf);

  const int q = blockIdx.x, tid = threadIdx.x;
  const int l = tid & 63, w = tid >> 6;
  unsigned long long* src = list + (size_t)q * CAPL;
  const unsigned qc = qcp[q];

  double qv_e = qv64[(size_t)q * Ed + tid];
  qr[tid] = qv_e;
  qf[tid] = (float)qv_e;
  __syncthreads();

  int count = (int)min(cnt[q], (unsigned)(CAPL + 256));

  // ---- fallback path (never expected): brute-force rebuild of list ----
  if (count < Mm || count > CAPL) {
    for (int j = tid; j < NBINS; j += 256) hist[j] = 0u;
    if (tid == 0) scnt = 0;
    __syncthreads();

    for (int i = tid; i < Ni; i += 256) {
      float s = 0.0f;
      const float* er = item + (size_t)i * Ed;
      for (int e = 0; e < Ed; ++e) s = fmaf(qf[e], er[e], s);
      if (!anybyte_eq(qc, icodes[i])) s -= 1.0e6f;
      atomicAdd(&hist[fkey(s) >> 19], 1u);
    }
    __syncthreads();

    int beta = find_beta(hist, partial_, &sbeta, tid, Mm);
    __syncthreads();

    for (int i = tid; i < Ni; i += 256) {
      float s = 0.0f;
      const float* er = item + (size_t)i * Ed;
      for (int e = 0; e < Ed; ++e) s = fmaf(qf[e], er[e], s);
      if (!anybyte_eq(qc, icodes[i])) s -= 1.0e6f;
      unsigned kk = fkey(s);
      if ((int)(kk >> 19) >= beta) {
        int pos = atomicAdd(&scnt, 1);
        if (pos < CAPL)
          src[pos] = ((unsigned long long)kk << 32) | (unsigned)(~(unsigned)i);
      }
    }
    __syncthreads();
    count = min(scnt, CAPL);
    __syncthreads();
  }

  // ---- select: histogram threshold + collect + bitonic ----
  for (int j = tid; j < NBINS; j += 256) hist[j] = 0u;
  if (tid == 0) scnt = 0;
  __syncthreads();

  for (int i = tid; i < count; i += 256)
    atomicAdd(&hist[(unsigned)(src[i] >> 32) >> 19], 1u);
  __syncthreads();

  int beta = find_beta(hist, partial_, &sbeta, tid, Mm);
  __syncthreads();   // hist dead; buf reuse begins

  for (int i = tid; i < count; i += 256) {
    unsigned long long v = src[i];
    if ((int)((unsigned)(v >> 32) >> 19) >= beta) {
      int pos = atomicAdd(&scnt, 1);
      if (pos < CAP2) buf[pos] = v;
    }
  }
  __syncthreads();

  int scv = min(scnt, CAP2);
  int n = Mm;
  while (n < scv) n <<= 1;
  for (int j = tid; j < n; j += 256)
    if (j >= scv) buf[j] = 0ull;
  __syncthreads();

  for (int k2 = 2; k2 <= n; k2 <<= 1) {
    for (int j = k2 >> 1; j > 0; j >>= 1) {
      for (int i = tid; i < n; i += 256) {
        int p = i ^ j;
        if (p > i) {
          bool up = ((i & k2) == 0);
          unsigned long long a = buf[i], b = buf[p];
          if ((a < b) == up) { buf[i] = b; buf[p] = a; }
        }
      }
      __syncthreads();
    }
  }

  if (tid < Mm) {
    int id = (int)(~(unsigned)(buf[tid] & 0xFFFFFFFFull));
    if (id < 0 || id >= Ni) id = 0;
    sid[tid] = id;
  }
  __syncthreads();

  // ---- rerank: f64 wave-cooperative dots + bitonic (score desc, id asc) ----
  for (int cc = 0; cc < Mm / 4; ++cc) {
    const int ci = w * (Mm / 4) + cc;
    const int id = sid[ci];
    float4 ev = *reinterpret_cast<const float4*>(&item[(size_t)id * Ed + l * 4]);
    double p = fma((double)ev.x, qr[l * 4 + 0],
               fma((double)ev.y, qr[l * 4 + 1],
               fma((double)ev.z, qr[l * 4 + 2],
                   (double)ev.w * qr[l * 4 + 3])));
#pragma unroll
    for (int off = 32; off > 0; off >>= 1) p += __shfl_down(p, off);
    if (l == 0) {
      double s = p;
      if (!anybyte_eq(qc, icodes[id])) s -= 1.0e6;
      sc[ci] = s;
    }
  }
  __syncthreads();

  for (int k2 = 2; k2 <= Mm; k2 <<= 1) {
    for (int j = k2 >> 1; j > 0; j >>= 1) {
      for (int i = tid; i < Mm; i += 256) {
        int p = i ^ j;
        if (p > i) {
          bool up = ((i & k2) == 0);
          double sa = sc[i], sb = sc[p];
          int ia = sid[i], ib = sid[p];
          bool aAfterB = (sa < sb) || (sa == sb && ia > ib);
          if (aAfterB == up) {
            sc[i] = sb; sc[p] = sa;
            sid[i] = ib; sid[p] = ia;
          }
        }
      }
      __syncthreads();
    }
  }

  if (tid < Kk) out_ids[q * Kk + tid] = (float)sid[tid];
  for (int f = tid; f < Kk * 64; f += 256) {
    int r = f >> 6, c4 = f & 63;
    *reinterpret_cast<float4*>(&out_emb[((size_t)q * Kk + r) * Ed + c4 * 4]) =
        *reinterpret_cast<const float4*>(&item[(size_t)sid[r] * Ed + c4 * 4]);
  }
}

// ---------------------------------------------------------------------------
extern "C" void kernel_launch(void* const* d_in, const int* in_sizes, int n_in,
                              void* d_out, int out_size, void* d_ws, size_t ws_size,
                              hipStream_t stream) {
  const float* hidden = (const float*)d_in[0];
  const float* Wq     = (const float*)d_in[1];
  const float* bq     = (const float*)d_in[2];
  const float* gamma  = (const float*)d_in[3];
  const float* beta   = (const float*)d_in[4];
  const float* proj   = (const float*)d_in[5];
  const float* item   = (const float*)d_in[6];

  float* out = (float*)d_out;
  char* ws = (char*)d_ws;
  double*             qv64 = (double*)(ws + OFF_QV64);
  unsigned*           qcp  = (unsigned*)(ws + OFF_QC);
  unsigned*           ic   = (unsigned*)(ws + OFF_IC);
  unsigned*           cnt  = (unsigned*)(ws + OFF_CNT);
  unsigned long long* list = (unsigned long long*)(ws + OFF_LIST);
  double*             part = (double*)(ws + OFF_PART);

  qp_icode_kernel<<<dim3(QT * KC + Ni / IPB), dim3(256), 0, stream>>>(
      hidden, Wq, part, item, proj, ic);
  qproj_fin<<<dim3(Bq), dim3(256), 0, stream>>>(part, bq, gamma, beta, proj,
                                                out, qv64, qcp, cnt);
  score_kernel<<<dim3(NSLICE * (Bq / QPS)), dim3(256), 0, stream>>>(
      out, item, ic, qcp, cnt, list);
  selrerank_kernel<<<dim3(Bq), dim3(256), 0, stream>>>(
      list, cnt, qv64, item, qcp, ic,
      out + (size_t)Bq * Ed, out + (size_t)Bq * Ed + (size_t)Bq * Kk);
}